// Round 1
// baseline (155.626 us; speedup 1.0000x reference)
//
#include <hip/hip_runtime.h>
#include <hip/hip_bf16.h>

#define DEV __device__ __forceinline__

typedef __attribute__((ext_vector_type(8))) short short8;
typedef __attribute__((ext_vector_type(4))) float f32x4;

constexpr int D   = 128;
constexpr int S   = 2048;
constexpr int Hh  = 4;
constexpr int DH  = 32;
constexpr float ETA_SCALE = 0.17677669529663687f;  // 1/sqrt(32)
constexpr float EPSV = 1e-5f;

DEV unsigned short f2b(float f) {
  __hip_bfloat16 h = __float2bfloat16(f);
  return *reinterpret_cast<unsigned short*>(&h);
}
DEV unsigned pack2(float a, float b) {
  return (unsigned)f2b(a) | ((unsigned)f2b(b) << 16);
}

// ---------------- prep: x -> bf16, weights -> bf16 transposed ----------------
__global__ __launch_bounds__(256) void prep_kernel(
    const float* __restrict__ x,
    const float* __restrict__ Wq, const float* __restrict__ Wk,
    const float* __restrict__ Wv, const float* __restrict__ Wo,
    const float* __restrict__ W1, const float* __restrict__ W2,
    unsigned short* __restrict__ xb,
    unsigned short* __restrict__ wqT, unsigned short* __restrict__ wkT,
    unsigned short* __restrict__ wvT, unsigned short* __restrict__ woT,
    unsigned short* __restrict__ w1T, unsigned short* __restrict__ w2T) {
  int b = blockIdx.x, t = threadIdx.x;
  if (b < 1024) {
    int i8 = (b * 256 + t) * 8;
    const float4* p = reinterpret_cast<const float4*>(x + i8);
    float4 v0 = p[0], v1 = p[1];
    short8 o;
    o[0] = (short)f2b(v0.x); o[1] = (short)f2b(v0.y);
    o[2] = (short)f2b(v0.z); o[3] = (short)f2b(v0.w);
    o[4] = (short)f2b(v1.x); o[5] = (short)f2b(v1.y);
    o[6] = (short)f2b(v1.z); o[7] = (short)f2b(v1.w);
    *reinterpret_cast<short8*>(xb + i8) = o;
    return;
  }
  const float* src; unsigned short* dst; int K, N, base;
  if      (b < 1088) { src = Wq; dst = wqT; K = 128; N = 128; base = 1024; }
  else if (b < 1152) { src = Wk; dst = wkT; K = 128; N = 128; base = 1088; }
  else if (b < 1216) { src = Wv; dst = wvT; K = 128; N = 128; base = 1152; }
  else if (b < 1280) { src = Wo; dst = woT; K = 128; N = 128; base = 1216; }
  else if (b < 1536) { src = W1; dst = w1T; K = 128; N = 512; base = 1280; }
  else               { src = W2; dst = w2T; K = 512; N = 128; base = 1536; }
  int idx = (b - base) * 256 + t;
  int k = idx / N, n = idx - k * N;
  dst[n * K + k] = f2b(src[idx]);
}

// ---------------- shared GEMM tile core ----------------
// A: [M][KDIM] bf16 row-major; BT: [N][KDIM] bf16 row-major (i.e. B transposed)
// wave computes rows row0..row0+15 x cols n0..n0+127 into acc[8] (f32x4 each).
template <int KDIM>
DEV void gemm_tile(const unsigned short* __restrict__ A,
                   const unsigned short* __restrict__ BT,
                   int row0, int n0, int ln, int g, f32x4 acc[8]) {
#pragma unroll
  for (int ks = 0; ks < KDIM; ks += 32) {
    short8 a = *reinterpret_cast<const short8*>(A + (size_t)(row0 + ln) * KDIM + ks + 8 * g);
#pragma unroll
    for (int c = 0; c < 8; ++c) {
      short8 b = *reinterpret_cast<const short8*>(BT + (size_t)(n0 + c * 16 + ln) * KDIM + ks + 8 * g);
      acc[c] = __builtin_amdgcn_mfma_f32_16x16x32_bf16(a, b, acc[c], 0, 0, 0);
    }
  }
}

// ---------------- QKV projection ----------------
// z = blockIdx.y: 0->q (eta*scale folded), 1->k, 2->v (written transposed)
__global__ __launch_bounds__(256) void qkv_kernel(
    const unsigned short* __restrict__ xb,
    const unsigned short* __restrict__ wqT, const unsigned short* __restrict__ wkT,
    const unsigned short* __restrict__ wvT,
    const float* __restrict__ bq, const float* __restrict__ bk, const float* __restrict__ bv,
    unsigned short* __restrict__ q, unsigned short* __restrict__ k,
    unsigned short* __restrict__ vT) {
  int w = threadIdx.x >> 6, lane = threadIdx.x & 63;
  int g = lane >> 4, ln = lane & 15;
  int z = blockIdx.y;
  int row0 = blockIdx.x * 64 + w * 16;
  const unsigned short* BT = (z == 0) ? wqT : (z == 1) ? wkT : wvT;
  const float* bias = (z == 0) ? bq : (z == 1) ? bk : bv;
  f32x4 acc[8];
#pragma unroll
  for (int c = 0; c < 8; ++c) acc[c] = f32x4{0.f, 0.f, 0.f, 0.f};
  gemm_tile<128>(xb, BT, row0, 0, ln, g, acc);
#pragma unroll
  for (int c = 0; c < 8; ++c) {
    int n = c * 16 + ln;
    int h = n >> 5, dh = n & 31;
    float bi = bias[n];
    if (z == 2) {
      int t0 = row0 + 4 * g;
      int b_ = t0 >> 11, s0 = t0 & 2047;
      size_t off = ((size_t)(b_ * Hh + h) * DH + dh) * S + s0;
      uint2 st;
      st.x = pack2(acc[c][0] + bi, acc[c][1] + bi);
      st.y = pack2(acc[c][2] + bi, acc[c][3] + bi);
      *reinterpret_cast<uint2*>(vT + off) = st;
    } else {
      float f = 1.0f;
      if (z == 0) f = (dh < 8) ? -ETA_SCALE : ETA_SCALE;
      unsigned short* dst = (z == 0) ? q : k;
#pragma unroll
      for (int r = 0; r < 4; ++r) {
        int t = row0 + 4 * g + r;
        int b_ = t >> 11, s = t & 2047;
        float v = (acc[c][r] + bi) * f;
        dst[((size_t)(b_ * Hh + h) * S + s) * DH + dh] = f2b(v);
      }
    }
  }
}

// ---------------- flash attention ----------------
// grid: (16 q-tiles, 32 bh). block: 4 waves, each wave owns 32 q rows.
__global__ __launch_bounds__(256) void attn_kernel(
    const unsigned short* __restrict__ q, const unsigned short* __restrict__ k,
    const unsigned short* __restrict__ vT, unsigned short* __restrict__ ao) {
  __shared__ unsigned short P_lds[4][32][72];  // per-wave [q_local][kv_local(+pad)]
  int w = threadIdx.x >> 6, lane = threadIdx.x & 63;
  int g = lane >> 4, ln = lane & 15;
  int bh = blockIdx.y;
  int qbase = blockIdx.x * 128 + w * 32;
  const unsigned short* qp = q + (size_t)bh * S * DH;
  const unsigned short* kp = k + (size_t)bh * S * DH;
  const unsigned short* vp = vT + (size_t)bh * DH * S;

  short8 qfr[2];
#pragma unroll
  for (int qf = 0; qf < 2; ++qf)
    qfr[qf] = *reinterpret_cast<const short8*>(qp + (size_t)(qbase + qf * 16 + ln) * DH + 8 * g);

  float m[2] = {-1e30f, -1e30f};
  float lsum[2] = {0.f, 0.f};
  f32x4 acc[2][2];  // [vf][qf], O^T fragments
#pragma unroll
  for (int a = 0; a < 2; ++a)
#pragma unroll
    for (int b = 0; b < 2; ++b) acc[a][b] = f32x4{0.f, 0.f, 0.f, 0.f};

  for (int kt = 0; kt < 32; ++kt) {
    int kv0 = kt * 64;
    short8 kf[4];
#pragma unroll
    for (int c = 0; c < 4; ++c)
      kf[c] = *reinterpret_cast<const short8*>(kp + (size_t)(kv0 + c * 16 + ln) * DH + 8 * g);
    f32x4 sst[4][2];
#pragma unroll
    for (int c = 0; c < 4; ++c)
#pragma unroll
      for (int qf = 0; qf < 2; ++qf)
        sst[c][qf] = __builtin_amdgcn_mfma_f32_16x16x32_bf16(kf[c], qfr[qf],
                                                             f32x4{0.f, 0.f, 0.f, 0.f}, 0, 0, 0);
    __syncthreads();  // prior PV reads done; also compiler fence before P writes
#pragma unroll
    for (int qf = 0; qf < 2; ++qf) {
      float pm = -1e30f;
#pragma unroll
      for (int c = 0; c < 4; ++c)
#pragma unroll
        for (int r = 0; r < 4; ++r) pm = fmaxf(pm, sst[c][qf][r]);
      pm = fmaxf(pm, __shfl_xor(pm, 16));
      pm = fmaxf(pm, __shfl_xor(pm, 32));
      float mnew = fmaxf(m[qf], pm);
      float cs = __expf(m[qf] - mnew);
      m[qf] = mnew;
      float psum = 0.f;
#pragma unroll
      for (int c = 0; c < 4; ++c)
#pragma unroll
        for (int r = 0; r < 4; ++r) {
          float p = __expf(sst[c][qf][r] - mnew);
          sst[c][qf][r] = p;
          psum += p;
        }
      psum += __shfl_xor(psum, 16);
      psum += __shfl_xor(psum, 32);
      lsum[qf] = lsum[qf] * cs + psum;
#pragma unroll
      for (int vf = 0; vf < 2; ++vf)
#pragma unroll
        for (int r = 0; r < 4; ++r) acc[vf][qf][r] *= cs;
#pragma unroll
      for (int c = 0; c < 4; ++c) {
        unsigned* dst = reinterpret_cast<unsigned*>(&P_lds[w][qf * 16 + ln][c * 16 + 4 * g]);
        dst[0] = pack2(sst[c][qf][0], sst[c][qf][1]);
        dst[1] = pack2(sst[c][qf][2], sst[c][qf][3]);
      }
    }
    __syncthreads();  // P visible before reads
#pragma unroll
    for (int hv = 0; hv < 2; ++hv) {
      short8 vfr[2];
#pragma unroll
      for (int vf = 0; vf < 2; ++vf)
        vfr[vf] = *reinterpret_cast<const short8*>(vp + (size_t)(vf * 16 + ln) * S + kv0 + hv * 32 + 8 * g);
#pragma unroll
      for (int qf = 0; qf < 2; ++qf) {
        short8 pf = *reinterpret_cast<const short8*>(&P_lds[w][qf * 16 + ln][hv * 32 + 8 * g]);
#pragma unroll
        for (int vf = 0; vf < 2; ++vf)
          acc[vf][qf] = __builtin_amdgcn_mfma_f32_16x16x32_bf16(vfr[vf], pf, acc[vf][qf], 0, 0, 0);
      }
    }
  }
  int b_ = bh >> 2, h = bh & 3;
#pragma unroll
  for (int qf = 0; qf < 2; ++qf) {
    float inv = 1.0f / lsum[qf];
    int qrow = qbase + qf * 16 + ln;
#pragma unroll
    for (int vf = 0; vf < 2; ++vf) {
      int dh0 = vf * 16 + 4 * g;
      uint2 st;
      st.x = pack2(acc[vf][qf][0] * inv, acc[vf][qf][1] * inv);
      st.y = pack2(acc[vf][qf][2] * inv, acc[vf][qf][3] * inv);
      *reinterpret_cast<uint2*>(ao + ((size_t)(b_ * S + qrow)) * D + h * DH + dh0) = st;
    }
  }
}

// ---------------- out-proj + residual + Minkowski LN ----------------
__global__ __launch_bounds__(256) void projln_kernel(
    const unsigned short* __restrict__ ao, const unsigned short* __restrict__ woT,
    const float* __restrict__ bo, const float* __restrict__ x,
    const float* __restrict__ g1t, const float* __restrict__ b1t,
    const float* __restrict__ g1s, const float* __restrict__ b1s,
    float* __restrict__ x1, unsigned short* __restrict__ x1b) {
  int w = threadIdx.x >> 6, lane = threadIdx.x & 63;
  int g = lane >> 4, ln = lane & 15;
  int row0 = blockIdx.x * 64 + w * 16;
  f32x4 acc[8];
#pragma unroll
  for (int c = 0; c < 8; ++c) acc[c] = f32x4{0.f, 0.f, 0.f, 0.f};
  gemm_tile<128>(ao, woT, row0, 0, ln, g, acc);
  float rv[8][4];
#pragma unroll
  for (int c = 0; c < 8; ++c) {
    int n = c * 16 + ln;
    float bi = bo[n];
#pragma unroll
    for (int r = 0; r < 4; ++r) {
      int t = row0 + 4 * g + r;
      rv[c][r] = acc[c][r] + bi + x[(size_t)t * D + n];
    }
  }
#pragma unroll
  for (int r = 0; r < 4; ++r) {
    float st = rv[0][r] + rv[1][r];
    float ss = 0.f;
#pragma unroll
    for (int c = 2; c < 8; ++c) ss += rv[c][r];
#pragma unroll
    for (int mm = 1; mm < 16; mm <<= 1) { st += __shfl_xor(st, mm); ss += __shfl_xor(ss, mm); }
    float mut = st * (1.f / 32.f), mus = ss * (1.f / 96.f);
    float vt = 0.f, vs = 0.f;
#pragma unroll
    for (int c = 0; c < 2; ++c) { float d = rv[c][r] - mut; vt += d * d; }
#pragma unroll
    for (int c = 2; c < 8; ++c) { float d = rv[c][r] - mus; vs += d * d; }
#pragma unroll
    for (int mm = 1; mm < 16; mm <<= 1) { vt += __shfl_xor(vt, mm); vs += __shfl_xor(vs, mm); }
    float rst = rsqrtf(vt * (1.f / 32.f) + EPSV);
    float rss = rsqrtf(vs * (1.f / 96.f) + EPSV);
    int t = row0 + 4 * g + r;
#pragma unroll
    for (int c = 0; c < 8; ++c) {
      int n = c * 16 + ln;
      float o = (c < 2) ? (rv[c][r] - mut) * rst * g1t[n] + b1t[n]
                        : (rv[c][r] - mus) * rss * g1s[n - 32] + b1s[n - 32];
      x1[(size_t)t * D + n] = o;
      x1b[(size_t)t * D + n] = f2b(o);
    }
  }
}

// ---------------- FFN1 + exact GELU ----------------
__global__ __launch_bounds__(256) void ffn1_kernel(
    const unsigned short* __restrict__ x1b, const unsigned short* __restrict__ w1T,
    const float* __restrict__ bf1, unsigned short* __restrict__ h) {
  int w = threadIdx.x >> 6, lane = threadIdx.x & 63;
  int g = lane >> 4, ln = lane & 15;
  int row0 = blockIdx.x * 64 + w * 16;
  int n0 = blockIdx.y * 128;
  f32x4 acc[8];
#pragma unroll
  for (int c = 0; c < 8; ++c) acc[c] = f32x4{0.f, 0.f, 0.f, 0.f};
  gemm_tile<128>(x1b, w1T, row0, n0, ln, g, acc);
#pragma unroll
  for (int c = 0; c < 8; ++c) {
    int n = n0 + c * 16 + ln;
    float bi = bf1[n];
#pragma unroll
    for (int r = 0; r < 4; ++r) {
      int t = row0 + 4 * g + r;
      float v = acc[c][r] + bi;
      float ge = 0.5f * v * (1.0f + erff(v * 0.70710678118654752f));
      h[(size_t)t * 512 + n] = f2b(ge);
    }
  }
}

// ---------------- FFN2 + residual + Minkowski LN ----------------
__global__ __launch_bounds__(256) void ffn2_kernel(
    const unsigned short* __restrict__ h, const unsigned short* __restrict__ w2T,
    const float* __restrict__ bf2, const float* __restrict__ x1,
    const float* __restrict__ g2t, const float* __restrict__ b2t,
    const float* __restrict__ g2s, const float* __restrict__ b2s,
    float* __restrict__ out) {
  int w = threadIdx.x >> 6, lane = threadIdx.x & 63;
  int g = lane >> 4, ln = lane & 15;
  int row0 = blockIdx.x * 64 + w * 16;
  f32x4 acc[8];
#pragma unroll
  for (int c = 0; c < 8; ++c) acc[c] = f32x4{0.f, 0.f, 0.f, 0.f};
  gemm_tile<512>(h, w2T, row0, 0, ln, g, acc);
  float rv[8][4];
#pragma unroll
  for (int c = 0; c < 8; ++c) {
    int n = c * 16 + ln;
    float bi = bf2[n];
#pragma unroll
    for (int r = 0; r < 4; ++r) {
      int t = row0 + 4 * g + r;
      rv[c][r] = acc[c][r] + bi + x1[(size_t)t * D + n];
    }
  }
#pragma unroll
  for (int r = 0; r < 4; ++r) {
    float st = rv[0][r] + rv[1][r];
    float ss = 0.f;
#pragma unroll
    for (int c = 2; c < 8; ++c) ss += rv[c][r];
#pragma unroll
    for (int mm = 1; mm < 16; mm <<= 1) { st += __shfl_xor(st, mm); ss += __shfl_xor(ss, mm); }
    float mut = st * (1.f / 32.f), mus = ss * (1.f / 96.f);
    float vt = 0.f, vs = 0.f;
#pragma unroll
    for (int c = 0; c < 2; ++c) { float d = rv[c][r] - mut; vt += d * d; }
#pragma unroll
    for (int c = 2; c < 8; ++c) { float d = rv[c][r] - mus; vs += d * d; }
#pragma unroll
    for (int mm = 1; mm < 16; mm <<= 1) { vt += __shfl_xor(vt, mm); vs += __shfl_xor(vs, mm); }
    float rst = rsqrtf(vt * (1.f / 32.f) + EPSV);
    float rss = rsqrtf(vs * (1.f / 96.f) + EPSV);
    int t = row0 + 4 * g + r;
#pragma unroll
    for (int c = 0; c < 8; ++c) {
      int n = c * 16 + ln;
      float o = (c < 2) ? (rv[c][r] - mut) * rst * g2t[n] + b2t[n]
                        : (rv[c][r] - mus) * rss * g2s[n - 32] + b2s[n - 32];
      out[(size_t)t * D + n] = o;
    }
  }
}

extern "C" void kernel_launch(void* const* d_in, const int* in_sizes, int n_in,
                              void* d_out, int out_size, void* d_ws, size_t ws_size,
                              hipStream_t stream) {
  (void)in_sizes; (void)n_in; (void)out_size; (void)ws_size;
  const float* x   = (const float*)d_in[0];
  const float* Wq  = (const float*)d_in[1];
  const float* bq  = (const float*)d_in[2];
  const float* Wk  = (const float*)d_in[3];
  const float* bk  = (const float*)d_in[4];
  const float* Wv  = (const float*)d_in[5];
  const float* bv  = (const float*)d_in[6];
  const float* Wo  = (const float*)d_in[7];
  const float* bo  = (const float*)d_in[8];
  const float* g1t = (const float*)d_in[9];
  const float* b1t = (const float*)d_in[10];
  const float* g1s = (const float*)d_in[11];
  const float* b1s = (const float*)d_in[12];
  const float* W1  = (const float*)d_in[13];
  const float* bf1 = (const float*)d_in[14];
  const float* W2  = (const float*)d_in[15];
  const float* bf2 = (const float*)d_in[16];
  const float* g2t = (const float*)d_in[17];
  const float* b2t = (const float*)d_in[18];
  const float* g2s = (const float*)d_in[19];
  const float* b2s = (const float*)d_in[20];

  char* ws = (char*)d_ws;
  unsigned short* xb  = (unsigned short*)(ws);                 // 16384x128 bf16
  unsigned short* wqT = (unsigned short*)(ws + 4194304);
  unsigned short* wkT = wqT + 16384;
  unsigned short* wvT = wkT + 16384;
  unsigned short* woT = wvT + 16384;
  unsigned short* w1T = woT + 16384;   // [512][128]
  unsigned short* w2T = w1T + 65536;   // [128][512]
  unsigned short* qb  = w2T + 65536;   // [8][4][2048][32]
  unsigned short* kb  = qb + 2097152;
  unsigned short* vT  = kb + 2097152;  // [8][4][32][2048]
  unsigned short* ao  = vT + 2097152;  // [16384][128]
  float* x1           = (float*)(ao + 2097152);      // [16384][128] f32
  unsigned short* x1b = (unsigned short*)(x1 + 2097152);
  unsigned short* hbf = x1b + 2097152; // [16384][512]
  float* outp = (float*)d_out;

  prep_kernel<<<1792, 256, 0, stream>>>(x, Wq, Wk, Wv, Wo, W1, W2,
                                        xb, wqT, wkT, wvT, woT, w1T, w2T);
  qkv_kernel<<<dim3(256, 3), 256, 0, stream>>>(xb, wqT, wkT, wvT, bq, bk, bv, qb, kb, vT);
  attn_kernel<<<dim3(16, 32), 256, 0, stream>>>(qb, kb, vT, ao);
  projln_kernel<<<256, 256, 0, stream>>>(ao, woT, bo, x, g1t, b1t, g1s, b1s, x1, x1b);
  ffn1_kernel<<<dim3(256, 4), 256, 0, stream>>>(x1b, w1T, bf1, hbf);
  ffn2_kernel<<<256, 256, 0, stream>>>(hbf, w2T, bf2, x1, g2t, b2t, g2s, b2s, outp);
}

// Round 2
// 133.682 us; speedup vs baseline: 1.1642x; 1.1642x over previous
//
#include <hip/hip_runtime.h>
#include <hip/hip_bf16.h>

#define DEV __device__ __forceinline__

typedef __attribute__((ext_vector_type(8))) short short8;
typedef __attribute__((ext_vector_type(4))) float f32x4;

constexpr int D   = 128;
constexpr int S   = 2048;
constexpr int Hh  = 4;
constexpr int DH  = 32;
// 1/sqrt(32) * log2(e): QK^T logits land directly in exp2 domain.
constexpr float QSCALE = 0.17677669529663687f * 1.4426950408889634f;
constexpr float EPSV = 1e-5f;

DEV unsigned short f2b(float f) {
  __hip_bfloat16 h = __float2bfloat16(f);
  return *reinterpret_cast<unsigned short*>(&h);
}
DEV unsigned pack2(float a, float b) {
  return (unsigned)f2b(a) | ((unsigned)f2b(b) << 16);
}

// ---------------- prep: x -> bf16, weights -> bf16 transposed ----------------
__global__ __launch_bounds__(256) void prep_kernel(
    const float* __restrict__ x,
    const float* __restrict__ Wq, const float* __restrict__ Wk,
    const float* __restrict__ Wv, const float* __restrict__ Wo,
    const float* __restrict__ W1, const float* __restrict__ W2,
    unsigned short* __restrict__ xb,
    unsigned short* __restrict__ wqT, unsigned short* __restrict__ wkT,
    unsigned short* __restrict__ wvT, unsigned short* __restrict__ woT,
    unsigned short* __restrict__ w1T, unsigned short* __restrict__ w2T) {
  int b = blockIdx.x, t = threadIdx.x;
  if (b < 1024) {
    int i8 = (b * 256 + t) * 8;
    const float4* p = reinterpret_cast<const float4*>(x + i8);
    float4 v0 = p[0], v1 = p[1];
    short8 o;
    o[0] = (short)f2b(v0.x); o[1] = (short)f2b(v0.y);
    o[2] = (short)f2b(v0.z); o[3] = (short)f2b(v0.w);
    o[4] = (short)f2b(v1.x); o[5] = (short)f2b(v1.y);
    o[6] = (short)f2b(v1.z); o[7] = (short)f2b(v1.w);
    *reinterpret_cast<short8*>(xb + i8) = o;
    return;
  }
  const float* src; unsigned short* dst; int K, N, base;
  if      (b < 1088) { src = Wq; dst = wqT; K = 128; N = 128; base = 1024; }
  else if (b < 1152) { src = Wk; dst = wkT; K = 128; N = 128; base = 1088; }
  else if (b < 1216) { src = Wv; dst = wvT; K = 128; N = 128; base = 1152; }
  else if (b < 1280) { src = Wo; dst = woT; K = 128; N = 128; base = 1216; }
  else if (b < 1536) { src = W1; dst = w1T; K = 128; N = 512; base = 1280; }
  else               { src = W2; dst = w2T; K = 512; N = 128; base = 1536; }
  int idx = (b - base) * 256 + t;
  int k = idx / N, n = idx - k * N;
  dst[n * K + k] = f2b(src[idx]);
}

// ---------------- shared GEMM tile core ----------------
// A: [M][KDIM] bf16 row-major; BT: [N][KDIM] bf16 row-major (B transposed).
// SWAP=false: acc[c] holds C rows t=row0+4g+r, col n=n0+16c+ln.
// SWAP=true : acc[c] holds C^T: token t=row0+ln (fixed/lane), cols n=n0+16c+4g+r.
template <int KDIM, bool SWAP>
DEV void gemm_tile(const unsigned short* __restrict__ A,
                   const unsigned short* __restrict__ BT,
                   int row0, int n0, int ln, int g, f32x4 acc[8]) {
#pragma unroll
  for (int ks = 0; ks < KDIM; ks += 32) {
    short8 a = *reinterpret_cast<const short8*>(A + (size_t)(row0 + ln) * KDIM + ks + 8 * g);
#pragma unroll
    for (int c = 0; c < 8; ++c) {
      short8 b = *reinterpret_cast<const short8*>(BT + (size_t)(n0 + c * 16 + ln) * KDIM + ks + 8 * g);
      if constexpr (SWAP)
        acc[c] = __builtin_amdgcn_mfma_f32_16x16x32_bf16(b, a, acc[c], 0, 0, 0);
      else
        acc[c] = __builtin_amdgcn_mfma_f32_16x16x32_bf16(a, b, acc[c], 0, 0, 0);
    }
  }
}

// ---------------- QKV projection ----------------
// z: 0->q (eta*scale*log2e folded, [bh][s][dh]), 1->k ([bh][s][dh]), 2->v^T ([bh][dh][s])
__global__ __launch_bounds__(256) void qkv_kernel(
    const unsigned short* __restrict__ xb,
    const unsigned short* __restrict__ wqT, const unsigned short* __restrict__ wkT,
    const unsigned short* __restrict__ wvT,
    const float* __restrict__ bq, const float* __restrict__ bk, const float* __restrict__ bv,
    unsigned short* __restrict__ q, unsigned short* __restrict__ k,
    unsigned short* __restrict__ vT) {
  int w = threadIdx.x >> 6, lane = threadIdx.x & 63;
  int g = lane >> 4, ln = lane & 15;
  int z = blockIdx.y;
  int row0 = blockIdx.x * 64 + w * 16;
  const unsigned short* BT = (z == 0) ? wqT : (z == 1) ? wkT : wvT;
  const float* bias = (z == 0) ? bq : (z == 1) ? bk : bv;
  f32x4 acc[8];
#pragma unroll
  for (int c = 0; c < 8; ++c) acc[c] = f32x4{0.f, 0.f, 0.f, 0.f};
  if (z == 2) {
    gemm_tile<128, false>(xb, BT, row0, 0, ln, g, acc);
#pragma unroll
    for (int c = 0; c < 8; ++c) {
      int n = c * 16 + ln;
      int h = n >> 5, dh = n & 31;
      float bi = bias[n];
      int t0 = row0 + 4 * g;
      int b_ = t0 >> 11, s0 = t0 & 2047;
      size_t off = ((size_t)(b_ * Hh + h) * DH + dh) * S + s0;
      uint2 st;
      st.x = pack2(acc[c][0] + bi, acc[c][1] + bi);
      st.y = pack2(acc[c][2] + bi, acc[c][3] + bi);
      *reinterpret_cast<uint2*>(vT + off) = st;
    }
  } else {
    gemm_tile<128, true>(xb, BT, row0, 0, ln, g, acc);
    unsigned short* dst = (z == 0) ? q : k;
    int t = row0 + ln;
    int b_ = t >> 11, s = t & 2047;
#pragma unroll
    for (int c = 0; c < 8; ++c) {
      int nc = c * 16 + 4 * g;
      int h = nc >> 5, dh0 = nc & 31;
      f32x4 bi = *reinterpret_cast<const f32x4*>(bias + nc);
      float f = 1.0f;
      if (z == 0) f = (dh0 < 8) ? -QSCALE : QSCALE;
      float v0 = (acc[c][0] + bi[0]) * f, v1 = (acc[c][1] + bi[1]) * f;
      float v2 = (acc[c][2] + bi[2]) * f, v3 = (acc[c][3] + bi[3]) * f;
      uint2 st;
      st.x = pack2(v0, v1);
      st.y = pack2(v2, v3);
      *reinterpret_cast<uint2*>(dst + ((size_t)(b_ * Hh + h) * S + s) * DH + dh0) = st;
    }
  }
}

// ---------------- flash attention ----------------
// grid: (16 q-tiles of 128, 32 bh). block: 512 thr = 8 waves.
// wave w: w_q = w>>1 (32 q rows), w_kv = w&1 (1024-kv half). No inner barriers:
// P buffer is wave-private; partials merged once at the end via LDS.
__global__ __launch_bounds__(512, 4) void attn_kernel(
    const unsigned short* __restrict__ q, const unsigned short* __restrict__ k,
    const unsigned short* __restrict__ vT, unsigned short* __restrict__ ao) {
  __shared__ unsigned short P_lds[8][32][72];
  __shared__ float mbuf[4][64][20];
  int w = threadIdx.x >> 6, lane = threadIdx.x & 63;
  int g = lane >> 4, ln = lane & 15;
  int w_q = w >> 1, w_kv = w & 1;
  int bh = blockIdx.y;
  int qbase = blockIdx.x * 128 + w_q * 32;
  const unsigned short* qp = q + (size_t)bh * S * DH;
  const unsigned short* kp = k + (size_t)bh * S * DH;
  const unsigned short* vp = vT + (size_t)bh * DH * S;

  short8 qfr[2];
#pragma unroll
  for (int qf = 0; qf < 2; ++qf)
    qfr[qf] = *reinterpret_cast<const short8*>(qp + (size_t)(qbase + qf * 16 + ln) * DH + 8 * g);

  float m[2] = {-1e30f, -1e30f};
  float lsum[2] = {0.f, 0.f};
  f32x4 acc[2][2];  // [vf][qf] O^T fragments
#pragma unroll
  for (int a = 0; a < 2; ++a)
#pragma unroll
    for (int b = 0; b < 2; ++b) acc[a][b] = f32x4{0.f, 0.f, 0.f, 0.f};

  for (int kt = 0; kt < 16; ++kt) {
    int kv0 = w_kv * 1024 + kt * 64;
    short8 kf[4];
#pragma unroll
    for (int c = 0; c < 4; ++c)
      kf[c] = *reinterpret_cast<const short8*>(kp + (size_t)(kv0 + c * 16 + ln) * DH + 8 * g);
    f32x4 sst[4][2];
#pragma unroll
    for (int c = 0; c < 4; ++c)
#pragma unroll
      for (int qf = 0; qf < 2; ++qf)
        sst[c][qf] = __builtin_amdgcn_mfma_f32_16x16x32_bf16(kf[c], qfr[qf],
                                                             f32x4{0.f, 0.f, 0.f, 0.f}, 0, 0, 0);
    short8 vfr[2][2];
#pragma unroll
    for (int hv = 0; hv < 2; ++hv)
#pragma unroll
      for (int vf = 0; vf < 2; ++vf)
        vfr[hv][vf] = *reinterpret_cast<const short8*>(vp + (size_t)(vf * 16 + ln) * S + kv0 + hv * 32 + 8 * g);
#pragma unroll
    for (int qf = 0; qf < 2; ++qf) {
      float pm = sst[0][qf][0];
#pragma unroll
      for (int c = 0; c < 4; ++c)
#pragma unroll
        for (int r = 0; r < 4; ++r) pm = fmaxf(pm, sst[c][qf][r]);
      pm = fmaxf(pm, __shfl_xor(pm, 16));
      pm = fmaxf(pm, __shfl_xor(pm, 32));
      // defer-max: skip rescale while tile max stays within 2^8 of running max
      if (!__all(pm <= m[qf] + 8.0f)) {
        float mnew = fmaxf(m[qf], pm);
        float cs = exp2f(m[qf] - mnew);
        m[qf] = mnew;
        lsum[qf] *= cs;
#pragma unroll
        for (int vf = 0; vf < 2; ++vf)
#pragma unroll
          for (int r = 0; r < 4; ++r) acc[vf][qf][r] *= cs;
      }
      float psum = 0.f;
#pragma unroll
      for (int c = 0; c < 4; ++c)
#pragma unroll
        for (int r = 0; r < 4; ++r) {
          float p = exp2f(sst[c][qf][r] - m[qf]);
          sst[c][qf][r] = p;
          psum += p;
        }
      psum += __shfl_xor(psum, 16);
      psum += __shfl_xor(psum, 32);
      lsum[qf] += psum;
#pragma unroll
      for (int c = 0; c < 4; ++c) {
        uint2 st;
        st.x = pack2(sst[c][qf][0], sst[c][qf][1]);
        st.y = pack2(sst[c][qf][2], sst[c][qf][3]);
        *reinterpret_cast<uint2*>(&P_lds[w][qf * 16 + ln][c * 16 + 4 * g]) = st;
      }
    }
#pragma unroll
    for (int hv = 0; hv < 2; ++hv)
#pragma unroll
      for (int qf = 0; qf < 2; ++qf) {
        short8 pf = *reinterpret_cast<const short8*>(&P_lds[w][qf * 16 + ln][hv * 32 + 8 * g]);
#pragma unroll
        for (int vf = 0; vf < 2; ++vf)
          acc[vf][qf] = __builtin_amdgcn_mfma_f32_16x16x32_bf16(vfr[hv][vf], pf, acc[vf][qf], 0, 0, 0);
      }
  }
  __syncthreads();
  if (w_kv == 1) {
    float* mb = mbuf[w_q][lane];
    mb[0] = m[0]; mb[1] = m[1]; mb[2] = lsum[0]; mb[3] = lsum[1];
#pragma unroll
    for (int vf = 0; vf < 2; ++vf)
#pragma unroll
      for (int qf = 0; qf < 2; ++qf)
#pragma unroll
        for (int r = 0; r < 4; ++r) mb[4 + (vf * 2 + qf) * 4 + r] = acc[vf][qf][r];
  }
  __syncthreads();
  if (w_kv == 0) {
    const float* mb = mbuf[w_q][lane];
    int b_ = bh >> 2, h = bh & 3;
#pragma unroll
    for (int qf = 0; qf < 2; ++qf) {
      float m2 = mb[qf], l2 = mb[2 + qf];
      float mt = fmaxf(m[qf], m2);
      float e1 = exp2f(m[qf] - mt), e2 = exp2f(m2 - mt);
      float inv = 1.0f / (lsum[qf] * e1 + l2 * e2);
      int qrow = qbase + qf * 16 + ln;
#pragma unroll
      for (int vf = 0; vf < 2; ++vf) {
        int dh0 = vf * 16 + 4 * g;
        const float* ma = mb + 4 + (vf * 2 + qf) * 4;
        float o0 = (acc[vf][qf][0] * e1 + ma[0] * e2) * inv;
        float o1 = (acc[vf][qf][1] * e1 + ma[1] * e2) * inv;
        float o2 = (acc[vf][qf][2] * e1 + ma[2] * e2) * inv;
        float o3 = (acc[vf][qf][3] * e1 + ma[3] * e2) * inv;
        uint2 st;
        st.x = pack2(o0, o1);
        st.y = pack2(o2, o3);
        *reinterpret_cast<uint2*>(ao + ((size_t)(b_ * S + qrow)) * D + h * DH + dh0) = st;
      }
    }
  }
}

// ---------------- out-proj + residual + Minkowski LN ----------------
__global__ __launch_bounds__(256) void projln_kernel(
    const unsigned short* __restrict__ ao, const unsigned short* __restrict__ woT,
    const float* __restrict__ bo, const float* __restrict__ x,
    const float* __restrict__ g1t, const float* __restrict__ b1t,
    const float* __restrict__ g1s, const float* __restrict__ b1s,
    float* __restrict__ x1, unsigned short* __restrict__ x1b) {
  int w = threadIdx.x >> 6, lane = threadIdx.x & 63;
  int g = lane >> 4, ln = lane & 15;
  int row0 = blockIdx.x * 64 + w * 16;
  f32x4 acc[8];
#pragma unroll
  for (int c = 0; c < 8; ++c) acc[c] = f32x4{0.f, 0.f, 0.f, 0.f};
  gemm_tile<128, true>(ao, woT, row0, 0, ln, g, acc);
  int t = row0 + ln;
  float rv[8][4];
#pragma unroll
  for (int c = 0; c < 8; ++c) {
    int nc = c * 16 + 4 * g;
    f32x4 bi = *reinterpret_cast<const f32x4*>(bo + nc);
    f32x4 xr = *reinterpret_cast<const f32x4*>(x + (size_t)t * D + nc);
#pragma unroll
    for (int r = 0; r < 4; ++r) rv[c][r] = acc[c][r] + bi[r] + xr[r];
  }
  float st = 0.f, ss = 0.f;
#pragma unroll
  for (int c = 0; c < 2; ++c)
#pragma unroll
    for (int r = 0; r < 4; ++r) st += rv[c][r];
#pragma unroll
  for (int c = 2; c < 8; ++c)
#pragma unroll
    for (int r = 0; r < 4; ++r) ss += rv[c][r];
  st += __shfl_xor(st, 16); st += __shfl_xor(st, 32);
  ss += __shfl_xor(ss, 16); ss += __shfl_xor(ss, 32);
  float mut = st * (1.f / 32.f), mus = ss * (1.f / 96.f);
  float vt = 0.f, vs = 0.f;
#pragma unroll
  for (int c = 0; c < 2; ++c)
#pragma unroll
    for (int r = 0; r < 4; ++r) { float d = rv[c][r] - mut; vt += d * d; }
#pragma unroll
  for (int c = 2; c < 8; ++c)
#pragma unroll
    for (int r = 0; r < 4; ++r) { float d = rv[c][r] - mus; vs += d * d; }
  vt += __shfl_xor(vt, 16); vt += __shfl_xor(vt, 32);
  vs += __shfl_xor(vs, 16); vs += __shfl_xor(vs, 32);
  float rst = rsqrtf(vt * (1.f / 32.f) + EPSV);
  float rss = rsqrtf(vs * (1.f / 96.f) + EPSV);
#pragma unroll
  for (int c = 0; c < 8; ++c) {
    int nc = c * 16 + 4 * g;
    f32x4 ga, bb;
    if (c < 2) {
      ga = *reinterpret_cast<const f32x4*>(g1t + nc);
      bb = *reinterpret_cast<const f32x4*>(b1t + nc);
    } else {
      ga = *reinterpret_cast<const f32x4*>(g1s + nc - 32);
      bb = *reinterpret_cast<const f32x4*>(b1s + nc - 32);
    }
    f32x4 o4;
#pragma unroll
    for (int r = 0; r < 4; ++r)
      o4[r] = (c < 2) ? (rv[c][r] - mut) * rst * ga[r] + bb[r]
                      : (rv[c][r] - mus) * rss * ga[r] + bb[r];
    *reinterpret_cast<f32x4*>(x1 + (size_t)t * D + nc) = o4;
    uint2 sb;
    sb.x = pack2(o4[0], o4[1]);
    sb.y = pack2(o4[2], o4[3]);
    *reinterpret_cast<uint2*>(x1b + (size_t)t * D + nc) = sb;
  }
}

// ---------------- FFN1 + exact GELU ----------------
__global__ __launch_bounds__(256) void ffn1_kernel(
    const unsigned short* __restrict__ x1b, const unsigned short* __restrict__ w1T,
    const float* __restrict__ bf1, unsigned short* __restrict__ h) {
  int w = threadIdx.x >> 6, lane = threadIdx.x & 63;
  int g = lane >> 4, ln = lane & 15;
  int row0 = blockIdx.x * 64 + w * 16;
  int n0 = blockIdx.y * 128;
  f32x4 acc[8];
#pragma unroll
  for (int c = 0; c < 8; ++c) acc[c] = f32x4{0.f, 0.f, 0.f, 0.f};
  gemm_tile<128, true>(x1b, w1T, row0, n0, ln, g, acc);
  int t = row0 + ln;
#pragma unroll
  for (int c = 0; c < 8; ++c) {
    int nc = n0 + c * 16 + 4 * g;
    f32x4 bi = *reinterpret_cast<const f32x4*>(bf1 + nc);
    float ge[4];
#pragma unroll
    for (int r = 0; r < 4; ++r) {
      float v = acc[c][r] + bi[r];
      ge[r] = 0.5f * v * (1.0f + erff(v * 0.70710678118654752f));
    }
    uint2 stv;
    stv.x = pack2(ge[0], ge[1]);
    stv.y = pack2(ge[2], ge[3]);
    *reinterpret_cast<uint2*>(h + (size_t)t * 512 + nc) = stv;
  }
}

// ---------------- FFN2 + residual + Minkowski LN ----------------
__global__ __launch_bounds__(256) void ffn2_kernel(
    const unsigned short* __restrict__ h, const unsigned short* __restrict__ w2T,
    const float* __restrict__ bf2, const float* __restrict__ x1,
    const float* __restrict__ g2t, const float* __restrict__ b2t,
    const float* __restrict__ g2s, const float* __restrict__ b2s,
    float* __restrict__ out) {
  int w = threadIdx.x >> 6, lane = threadIdx.x & 63;
  int g = lane >> 4, ln = lane & 15;
  int row0 = blockIdx.x * 64 + w * 16;
  f32x4 acc[8];
#pragma unroll
  for (int c = 0; c < 8; ++c) acc[c] = f32x4{0.f, 0.f, 0.f, 0.f};
  gemm_tile<512, true>(h, w2T, row0, 0, ln, g, acc);
  int t = row0 + ln;
  float rv[8][4];
#pragma unroll
  for (int c = 0; c < 8; ++c) {
    int nc = c * 16 + 4 * g;
    f32x4 bi = *reinterpret_cast<const f32x4*>(bf2 + nc);
    f32x4 xr = *reinterpret_cast<const f32x4*>(x1 + (size_t)t * D + nc);
#pragma unroll
    for (int r = 0; r < 4; ++r) rv[c][r] = acc[c][r] + bi[r] + xr[r];
  }
  float st = 0.f, ss = 0.f;
#pragma unroll
  for (int c = 0; c < 2; ++c)
#pragma unroll
    for (int r = 0; r < 4; ++r) st += rv[c][r];
#pragma unroll
  for (int c = 2; c < 8; ++c)
#pragma unroll
    for (int r = 0; r < 4; ++r) ss += rv[c][r];
  st += __shfl_xor(st, 16); st += __shfl_xor(st, 32);
  ss += __shfl_xor(ss, 16); ss += __shfl_xor(ss, 32);
  float mut = st * (1.f / 32.f), mus = ss * (1.f / 96.f);
  float vt = 0.f, vs = 0.f;
#pragma unroll
  for (int c = 0; c < 2; ++c)
#pragma unroll
    for (int r = 0; r < 4; ++r) { float d = rv[c][r] - mut; vt += d * d; }
#pragma unroll
  for (int c = 2; c < 8; ++c)
#pragma unroll
    for (int r = 0; r < 4; ++r) { float d = rv[c][r] - mus; vs += d * d; }
  vt += __shfl_xor(vt, 16); vt += __shfl_xor(vt, 32);
  vs += __shfl_xor(vs, 16); vs += __shfl_xor(vs, 32);
  float rst = rsqrtf(vt * (1.f / 32.f) + EPSV);
  float rss = rsqrtf(vs * (1.f / 96.f) + EPSV);
#pragma unroll
  for (int c = 0; c < 8; ++c) {
    int nc = c * 16 + 4 * g;
    f32x4 ga, bb;
    if (c < 2) {
      ga = *reinterpret_cast<const f32x4*>(g2t + nc);
      bb = *reinterpret_cast<const f32x4*>(b2t + nc);
    } else {
      ga = *reinterpret_cast<const f32x4*>(g2s + nc - 32);
      bb = *reinterpret_cast<const f32x4*>(b2s + nc - 32);
    }
    f32x4 o4;
#pragma unroll
    for (int r = 0; r < 4; ++r)
      o4[r] = (c < 2) ? (rv[c][r] - mut) * rst * ga[r] + bb[r]
                      : (rv[c][r] - mus) * rss * ga[r] + bb[r];
    *reinterpret_cast<f32x4*>(out + (size_t)t * D + nc) = o4;
  }
}

extern "C" void kernel_launch(void* const* d_in, const int* in_sizes, int n_in,
                              void* d_out, int out_size, void* d_ws, size_t ws_size,
                              hipStream_t stream) {
  (void)in_sizes; (void)n_in; (void)out_size; (void)ws_size;
  const float* x   = (const float*)d_in[0];
  const float* Wq  = (const float*)d_in[1];
  const float* bq  = (const float*)d_in[2];
  const float* Wk  = (const float*)d_in[3];
  const float* bk  = (const float*)d_in[4];
  const float* Wv  = (const float*)d_in[5];
  const float* bv  = (const float*)d_in[6];
  const float* Wo  = (const float*)d_in[7];
  const float* bo  = (const float*)d_in[8];
  const float* g1t = (const float*)d_in[9];
  const float* b1t = (const float*)d_in[10];
  const float* g1s = (const float*)d_in[11];
  const float* b1s = (const float*)d_in[12];
  const float* W1  = (const float*)d_in[13];
  const float* bf1 = (const float*)d_in[14];
  const float* W2  = (const float*)d_in[15];
  const float* bf2 = (const float*)d_in[16];
  const float* g2t = (const float*)d_in[17];
  const float* b2t = (const float*)d_in[18];
  const float* g2s = (const float*)d_in[19];
  const float* b2s = (const float*)d_in[20];

  char* ws = (char*)d_ws;
  unsigned short* xb  = (unsigned short*)(ws);                 // 16384x128 bf16
  unsigned short* wqT = (unsigned short*)(ws + 4194304);
  unsigned short* wkT = wqT + 16384;
  unsigned short* wvT = wkT + 16384;
  unsigned short* woT = wvT + 16384;
  unsigned short* w1T = woT + 16384;   // [512][128]
  unsigned short* w2T = w1T + 65536;   // [128][512]
  unsigned short* qb  = w2T + 65536;   // [8][4][2048][32]
  unsigned short* kb  = qb + 2097152;
  unsigned short* vT  = kb + 2097152;  // [8][4][32][2048]
  unsigned short* ao  = vT + 2097152;  // [16384][128]
  float* x1           = (float*)(ao + 2097152);      // [16384][128] f32
  unsigned short* x1b = (unsigned short*)(x1 + 2097152);
  unsigned short* hbf = x1b + 2097152; // [16384][512]
  float* outp = (float*)d_out;

  prep_kernel<<<1792, 256, 0, stream>>>(x, Wq, Wk, Wv, Wo, W1, W2,
                                        xb, wqT, wkT, wvT, woT, w1T, w2T);
  qkv_kernel<<<dim3(256, 3), 256, 0, stream>>>(xb, wqT, wkT, wvT, bq, bk, bv, qb, kb, vT);
  attn_kernel<<<dim3(16, 32), 512, 0, stream>>>(qb, kb, vT, ao);
  projln_kernel<<<256, 256, 0, stream>>>(ao, woT, bo, x, g1t, b1t, g1s, b1s, x1, x1b);
  ffn1_kernel<<<dim3(256, 4), 256, 0, stream>>>(x1b, w1T, bf1, hbf);
  ffn2_kernel<<<256, 256, 0, stream>>>(hbf, w2T, bf2, x1, g2t, b2t, g2s, b2s, outp);
}